// Round 5
// baseline (1616.395 us; speedup 1.0000x reference)
//
#include <hip/hip_runtime.h>
#include <cmath>

namespace {

constexpr int BB = 8192;
constexpr int TT = 512;
constexpr int FF = 2048;
constexpr float EPS_LN  = 1e-5f;
constexpr float EPS_SIG = 1e-8f;

typedef _Float16 half8 __attribute__((ext_vector_type(8)));
typedef _Float16 half4 __attribute__((ext_vector_type(4)));
typedef float f32x4 __attribute__((ext_vector_type(4)));

__device__ __forceinline__ float silu_f(float v) {
    return v / (1.0f + expf(-v));
}

// ------------- fp32 -> f16 (hi, optional lo residual) weight conversion -------------
template <bool LO>
__global__ __launch_bounds__(256) void cvt_kernel(
    const float* __restrict__ s, _Float16* __restrict__ hi,
    _Float16* __restrict__ lo, int n) {
    int i = (blockIdx.x * 256 + threadIdx.x) * 4;
    if (i >= n) return;
    float4 v = *(const float4*)(s + i);
    half4 h;
    h[0] = (_Float16)v.x; h[1] = (_Float16)v.y;
    h[2] = (_Float16)v.z; h[3] = (_Float16)v.w;
    *(half4*)(hi + i) = h;
    if (LO) {
        half4 l;
        l[0] = (_Float16)(v.x - (float)h[0]);
        l[1] = (_Float16)(v.y - (float)h[1]);
        l[2] = (_Float16)(v.z - (float)h[2]);
        l[3] = (_Float16)(v.w - (float)h[3]);
        *(half4*)(lo + i) = l;
    }
}

// ---------------- tokenizer: Q[b,t] = silu(x . l1_w[t] + l1_b[t]) ----------------
__global__ __launch_bounds__(256) void tok_kernel(
    const float* __restrict__ x, const float* __restrict__ l1w,
    const float* __restrict__ l1b, float* __restrict__ Q) {
    int idx = blockIdx.x * 256 + threadIdx.x;          // < B*T
    int b = idx >> 9, t = idx & 511;
    float x0 = x[2 * b], x1 = x[2 * b + 1];
    float v = fmaf(x0, l1w[2 * t], fmaf(x1, l1w[2 * t + 1], l1b[t]));
    Q[idx] = silu_f(v);
}

// ------- layernorm (fp32 in, f16 out, optional f16 lo residual), wave per row -------
template <bool LO>
__global__ __launch_bounds__(256) void ln_kernel(
    const float* __restrict__ X, const float* __restrict__ g,
    const float* __restrict__ bia, _Float16* __restrict__ Y,
    _Float16* __restrict__ Ylo) {
    int lane = threadIdx.x & 63;
    int row  = blockIdx.x * 4 + (threadIdx.x >> 6);
    const float* xr = X + (size_t)row * TT;
    float v[8];
    {
        float4 a = *(const float4*)(xr + lane * 8);
        float4 c = *(const float4*)(xr + lane * 8 + 4);
        v[0]=a.x; v[1]=a.y; v[2]=a.z; v[3]=a.w;
        v[4]=c.x; v[5]=c.y; v[6]=c.z; v[7]=c.w;
    }
    float s = 0.f;
    #pragma unroll
    for (int i = 0; i < 8; ++i) s += v[i];
    #pragma unroll
    for (int off = 32; off > 0; off >>= 1) s += __shfl_down(s, off);
    float mean = __shfl(s, 0) * (1.0f / TT);
    float ss = 0.f;
    #pragma unroll
    for (int i = 0; i < 8; ++i) { float d = v[i] - mean; ss = fmaf(d, d, ss); }
    #pragma unroll
    for (int off = 32; off > 0; off >>= 1) ss += __shfl_down(ss, off);
    float var  = __shfl(ss, 0) * (1.0f / TT);
    float rstd = rsqrtf(var + EPS_LN);
    half8 hv, lv;
    #pragma unroll
    for (int i = 0; i < 8; ++i) {
        int t = lane * 8 + i;
        float o = (v[i] - mean) * rstd * g[t] + bia[t];
        hv[i] = (_Float16)o;
        if (LO) lv[i] = (_Float16)(o - (float)hv[i]);
    }
    *(half8*)(Y + (size_t)row * TT + lane * 8) = hv;
    if (LO) *(half8*)(Ylo + (size_t)row * TT + lane * 8) = lv;
}

// ------------- barrier-free register-fragment MFMA GEMM -------------
// C[M,N] = act(A[M,K] @ W[N,K]^T + b) (+R). No LDS, no __syncthreads.
// Each wave owns a WM x 64 C-tile. A/B fragments are loaded global->VGPR
// (16 rows x 64 B contiguous per instruction), software-pipelined one
// BK=32 iteration ahead (ping-pong register sets). Compiler emits per-wave
// s_waitcnt vmcnt(N) at first use -- no block-wide vmcnt(0) drain exists.
// SPLIT: acc = A@W + Alo@W + A@Wlo (near-fp32 from f16 inputs).
// Wave id -> tile: m fastest (consecutive waves share the same W columns).
template <int WM, int ACT, bool RESID, bool SPLIT, typename OutT>
__global__ __launch_bounds__(256) void rgemm_kernel(
    const _Float16* __restrict__ A, const _Float16* __restrict__ Alo,
    const _Float16* __restrict__ W, const _Float16* __restrict__ Wlo,
    const float* __restrict__ bias, const float* __restrict__ R,
    OutT* __restrict__ C, int N, int K, int nwx) {
    constexpr int MI = WM / 16;
    constexpr int NI = 4;                 // 64 columns per wave

    const int wid  = blockIdx.x * 4 + (threadIdx.x >> 6);
    const int wm   = (wid % nwx) * WM;
    const int wn   = (wid / nwx) * 64;
    const int lane = threadIdx.x & 63;
    const int fr   = lane & 15;
    const int q    = lane >> 4;           // k-chunk: halves q*8..q*8+7

    const _Float16* Ap  = A + (size_t)(wm + fr) * K + q * 8;
    const _Float16* Wp  = W + (size_t)(wn + fr) * K + q * 8;
    const _Float16* Ap2 = SPLIT ? (Alo + (size_t)(wm + fr) * K + q * 8) : nullptr;
    const _Float16* Wp2 = SPLIT ? (Wlo + (size_t)(wn + fr) * K + q * 8) : nullptr;

    f32x4 acc[MI][NI];
    #pragma unroll
    for (int mi = 0; mi < MI; ++mi)
        #pragma unroll
        for (int ni = 0; ni < NI; ++ni) acc[mi][ni] = {0.f, 0.f, 0.f, 0.f};

    half8 a0[MI], b0[NI], a1[MI], b1[NI];
    half8 al0[SPLIT ? MI : 1], bl0[SPLIT ? NI : 1];
    half8 al1[SPLIT ? MI : 1], bl1[SPLIT ? NI : 1];

#define LOADSET(AV, BV, ALV, BLV, KO)                                          \
    do {                                                                       \
        _Pragma("unroll")                                                      \
        for (int mi = 0; mi < MI; ++mi)                                        \
            AV[mi] = *(const half8*)(Ap + (size_t)mi * 16 * K + (KO));         \
        _Pragma("unroll")                                                      \
        for (int ni = 0; ni < NI; ++ni)                                        \
            BV[ni] = *(const half8*)(Wp + (size_t)ni * 16 * K + (KO));         \
        if (SPLIT) {                                                           \
            _Pragma("unroll")                                                  \
            for (int mi = 0; mi < MI; ++mi)                                    \
                ALV[mi] = *(const half8*)(Ap2 + (size_t)mi * 16 * K + (KO));   \
            _Pragma("unroll")                                                  \
            for (int ni = 0; ni < NI; ++ni)                                    \
                BLV[ni] = *(const half8*)(Wp2 + (size_t)ni * 16 * K + (KO));   \
        }                                                                      \
    } while (0)

#define MFMASET(AV, BV, ALV, BLV)                                              \
    do {                                                                       \
        _Pragma("unroll")                                                      \
        for (int mi = 0; mi < MI; ++mi)                                        \
            _Pragma("unroll")                                                  \
            for (int ni = 0; ni < NI; ++ni)                                    \
                acc[mi][ni] = __builtin_amdgcn_mfma_f32_16x16x32_f16(          \
                    AV[mi], BV[ni], acc[mi][ni], 0, 0, 0);                     \
        if (SPLIT) {                                                           \
            _Pragma("unroll")                                                  \
            for (int mi = 0; mi < MI; ++mi)                                    \
                _Pragma("unroll")                                              \
                for (int ni = 0; ni < NI; ++ni)                                \
                    acc[mi][ni] = __builtin_amdgcn_mfma_f32_16x16x32_f16(      \
                        ALV[mi], BV[ni], acc[mi][ni], 0, 0, 0);                \
            _Pragma("unroll")                                                  \
            for (int mi = 0; mi < MI; ++mi)                                    \
                _Pragma("unroll")                                              \
                for (int ni = 0; ni < NI; ++ni)                                \
                    acc[mi][ni] = __builtin_amdgcn_mfma_f32_16x16x32_f16(      \
                        AV[mi], BLV[ni], acc[mi][ni], 0, 0, 0);                \
        }                                                                      \
    } while (0)

    LOADSET(a0, b0, al0, bl0, 0);
    for (int k0 = 0; k0 < K; k0 += 64) {           // two BK=32 halves per pass
        LOADSET(a1, b1, al1, bl1, k0 + 32);
        MFMASET(a0, b0, al0, bl0);
        if (k0 + 64 < K) LOADSET(a0, b0, al0, bl0, k0 + 64);
        MFMASET(a1, b1, al1, bl1);
    }
#undef LOADSET
#undef MFMASET

    // C/D layout: col = lane&15, row = (lane>>4)*4 + reg
    const int r0 = q * 4;
    #pragma unroll
    for (int mi = 0; mi < MI; ++mi) {
        #pragma unroll
        for (int ni = 0; ni < NI; ++ni) {
            const int col = wn + ni * 16 + fr;
            const float bv = bias[col];
            #pragma unroll
            for (int r = 0; r < 4; ++r) {
                const int row = wm + mi * 16 + r0 + r;
                float v = acc[mi][ni][r] + bv;
                if (ACT == 1) v = silu_f(v);
                if (ACT == 2) v = tanhf(v);
                if (RESID) v += R[(size_t)row * N + col];
                C[(size_t)row * N + col] = (OutT)v;
            }
        }
    }
}

// ------- Gaussian kernelized attention update: Q += sum_k S(G,mu,sig)*H -------
__global__ __launch_bounds__(256) void attn_kernel(
    float* __restrict__ Q, const float* __restrict__ mu_,
    const float* __restrict__ sig_, const float* __restrict__ x,
    const float* __restrict__ omega, const float* __restrict__ G,
    const float* __restrict__ phase) {
    __shared__ float cs[8][260];
    __shared__ float gs[8][260];
    const int tid = threadIdx.x;
    const int b   = blockIdx.x >> 1;
    const int t0  = (blockIdx.x & 1) * 256;
    const float x0 = x[2 * b], x1 = x[2 * b + 1];
    #pragma unroll
    for (int it = 0; it < 8; ++it) {
        int j = it * 256 + tid;            // 0..2047
        int e = t0 * 8 + j;                // flat (t,k) index
        float2 om = *(const float2*)(omega + 2 * e);
        float arg = fmaf(om.x, x0, fmaf(om.y, x1, phase[e]));
        cs[j & 7][j >> 3] = __cosf(arg);
        gs[j & 7][j >> 3] = G[e];
    }
    __syncthreads();
    const int idx = blockIdx.x * 256 + tid;   // = b*512 + t0 + tid
    float mu  = mu_[idx];
    float sig = sig_[idx];
    float inv = -0.5f * __builtin_amdgcn_rcpf(fmaf(sig, sig, EPS_SIG));
    float acc = 0.f;
    #pragma unroll
    for (int k = 0; k < 8; ++k) {
        float d = gs[k][tid] - mu;
        acc = fmaf(__expf(d * d * inv), cs[k][tid], acc);
    }
    Q[idx] += acc;
}

// ---------------- readout: out[b] = silu(Q[b,:]) . ro_w + ro_b ----------------
__global__ __launch_bounds__(256) void readout_kernel(
    const float* __restrict__ Q, const float* __restrict__ row_,
    const float* __restrict__ rob, float* __restrict__ out) {
    int lane = threadIdx.x & 63;
    int row  = blockIdx.x * 4 + (threadIdx.x >> 6);
    const float* qr = Q + (size_t)row * TT;
    float acc = 0.f;
    #pragma unroll
    for (int i = 0; i < 8; ++i) {
        int t = lane * 8 + i;
        acc = fmaf(silu_f(qr[t]), row_[t], acc);
    }
    #pragma unroll
    for (int off = 32; off > 0; off >>= 1) acc += __shfl_down(acc, off);
    if (lane == 0) out[row] = acc + rob[0];
}

} // namespace

extern "C" void kernel_launch(void* const* d_in, const int* in_sizes, int n_in,
                              void* d_out, int out_size, void* d_ws, size_t ws_size,
                              hipStream_t stream) {
    const float* x     = (const float*)d_in[0];
    const float* omega = (const float*)d_in[1];
    const float* G     = (const float*)d_in[2];
    const float* phase = (const float*)d_in[3];
    const float* l1_w  = (const float*)d_in[4];
    const float* l1_b  = (const float*)d_in[5];
    const float* mu_w  = (const float*)d_in[6];
    const float* mu_b  = (const float*)d_in[7];
    const float* sg_w  = (const float*)d_in[8];
    const float* sg_b  = (const float*)d_in[9];
    const float* alqg  = (const float*)d_in[10];
    const float* alqb  = (const float*)d_in[11];
    const float* alfg  = (const float*)d_in[12];
    const float* alfb  = (const float*)d_in[13];
    const float* a_w1  = (const float*)d_in[14];
    const float* a_b1  = (const float*)d_in[15];
    const float* a_w2  = (const float*)d_in[16];
    const float* a_b2  = (const float*)d_in[17];
    const float* mln_g = (const float*)d_in[18];
    const float* mln_b = (const float*)d_in[19];
    const float* m_w1  = (const float*)d_in[20];
    const float* m_b1  = (const float*)d_in[21];
    const float* m_w2  = (const float*)d_in[22];
    const float* m_b2  = (const float*)d_in[23];
    const float* ro_w  = (const float*)d_in[24];
    const float* ro_b  = (const float*)d_in[25];

    // ---- workspace layout (total 100,663,296 B == round-1 proven footprint) ----
    char* ws = (char*)d_ws;
    float*     Q    = (float*)ws;                          // 16 MB  [B,T] fp32
    _Float16*  h_hi = (_Float16*)(ws + 16777216);          //  8 MB  [B,T] f16
    _Float16*  h_lo = (_Float16*)(ws + 25165824);          //  8 MB  [B,T] f16
    _Float16*  mid  = (_Float16*)(ws + 33554432);          // 32 MB  [B,F] f16
    float*     mu   = (float*)(ws + 33554432);             // alias on mid
    float*     sig  = (float*)(ws + 50331648);             // alias on mid
    _Float16*  wbuf = (_Float16*)(ws + 67108864);          // 32 MB  f16 weights

    _Float16* muw_hi = wbuf;                     // 4*512*512
    _Float16* muw_lo = muw_hi + 1048576;
    _Float16* sgw_hi = muw_lo + 1048576;
    _Float16* sgw_lo = sgw_hi + 1048576;
    _Float16* aw1    = sgw_lo + 1048576;         // 4*2048*512
    _Float16* aw2    = aw1 + 4194304;
    _Float16* mw1    = aw2 + 4194304;            // 2*2048*512
    _Float16* mw2    = mw1 + 2097152;

    dim3 blk(256);

    // weight conversion (re-done every call; inputs are re-poisoned by harness)
    cvt_kernel<true ><<<1024, blk, 0, stream>>>(mu_w, muw_hi, muw_lo, 1048576);
    cvt_kernel<true ><<<1024, blk, 0, stream>>>(sg_w, sgw_hi, sgw_lo, 1048576);
    cvt_kernel<false><<<4096, blk, 0, stream>>>(a_w1, aw1, nullptr, 4194304);
    cvt_kernel<false><<<4096, blk, 0, stream>>>(a_w2, aw2, nullptr, 4194304);
    cvt_kernel<false><<<2048, blk, 0, stream>>>(m_w1, mw1, nullptr, 2097152);
    cvt_kernel<false><<<2048, blk, 0, stream>>>(m_w2, mw2, nullptr, 2097152);

    tok_kernel<<<BB * TT / 256, blk, 0, stream>>>(x, l1_w, l1_b, Q);

    // wave grids: FFN1 (8192/64)x(2048/64)=4096 waves; mu/sig 1024; FFN2 WM=32 -> 2048
    for (int i = 0; i < 4; ++i) {
        ln_kernel<true><<<BB / 4, blk, 0, stream>>>(
            Q, alqg + i * TT, alqb + i * TT, h_hi, h_lo);
        rgemm_kernel<64, 2, false, true, float><<<256, blk, 0, stream>>>(
            h_hi, h_lo, muw_hi + (size_t)i * 262144, muw_lo + (size_t)i * 262144,
            mu_b + i * TT, nullptr, mu, TT, TT, 128);
        rgemm_kernel<64, 0, false, true, float><<<256, blk, 0, stream>>>(
            h_hi, h_lo, sgw_hi + (size_t)i * 262144, sgw_lo + (size_t)i * 262144,
            sg_b + i * TT, nullptr, sig, TT, TT, 128);
        attn_kernel<<<BB * TT / 256, blk, 0, stream>>>(Q, mu, sig, x, omega, G, phase);
        ln_kernel<false><<<BB / 4, blk, 0, stream>>>(
            Q, alfg + i * TT, alfb + i * TT, h_hi, nullptr);
        rgemm_kernel<64, 1, false, false, _Float16><<<1024, blk, 0, stream>>>(
            h_hi, nullptr, aw1 + (size_t)i * 1048576, nullptr,
            a_b1 + i * FF, nullptr, mid, FF, TT, 128);
        rgemm_kernel<32, 0, true, false, float><<<512, blk, 0, stream>>>(
            mid, nullptr, aw2 + (size_t)i * 1048576, nullptr,
            a_b2 + i * TT, Q, Q, TT, FF, 256);
    }
    for (int i = 0; i < 2; ++i) {
        ln_kernel<false><<<BB / 4, blk, 0, stream>>>(
            Q, mln_g + i * TT, mln_b + i * TT, h_hi, nullptr);
        rgemm_kernel<64, 1, false, false, _Float16><<<1024, blk, 0, stream>>>(
            h_hi, nullptr, mw1 + (size_t)i * 1048576, nullptr,
            m_b1 + i * FF, nullptr, mid, FF, TT, 128);
        rgemm_kernel<32, 0, true, false, float><<<512, blk, 0, stream>>>(
            mid, nullptr, mw2 + (size_t)i * 1048576, nullptr,
            m_b2 + i * TT, Q, Q, TT, FF, 256);
    }

    readout_kernel<<<BB / 4, blk, 0, stream>>>(Q, ro_w, ro_b, (float*)d_out);
}

// Round 6
// 966.532 us; speedup vs baseline: 1.6724x; 1.6724x over previous
//
#include <hip/hip_runtime.h>
#include <cmath>

namespace {

constexpr int BB = 8192;
constexpr int TT = 512;
constexpr int FF = 2048;
constexpr float EPS_LN  = 1e-5f;
constexpr float EPS_SIG = 1e-8f;

typedef _Float16 half8 __attribute__((ext_vector_type(8)));
typedef _Float16 half4 __attribute__((ext_vector_type(4)));
typedef float f32x4 __attribute__((ext_vector_type(4)));

typedef __attribute__((address_space(1))) void gvoid_t;
typedef __attribute__((address_space(3))) void lvoid_t;

__device__ __forceinline__ void async16(void* lds, const void* g) {
    __builtin_amdgcn_global_load_lds((gvoid_t*)g, (lvoid_t*)lds, 16, 0, 0);
}

__device__ __forceinline__ float silu_f(float v) {
    return v / (1.0f + expf(-v));
}

// ------------- fp32 -> f16 (hi, optional lo residual) weight conversion -------------
template <bool LO>
__global__ __launch_bounds__(256) void cvt_kernel(
    const float* __restrict__ s, _Float16* __restrict__ hi,
    _Float16* __restrict__ lo, int n) {
    int i = (blockIdx.x * 256 + threadIdx.x) * 4;
    if (i >= n) return;
    float4 v = *(const float4*)(s + i);
    half4 h;
    h[0] = (_Float16)v.x; h[1] = (_Float16)v.y;
    h[2] = (_Float16)v.z; h[3] = (_Float16)v.w;
    *(half4*)(hi + i) = h;
    if (LO) {
        half4 l;
        l[0] = (_Float16)(v.x - (float)h[0]);
        l[1] = (_Float16)(v.y - (float)h[1]);
        l[2] = (_Float16)(v.z - (float)h[2]);
        l[3] = (_Float16)(v.w - (float)h[3]);
        *(half4*)(lo + i) = l;
    }
}

// ---------------- tokenizer: Q[b,t] = silu(x . l1_w[t] + l1_b[t]) ----------------
__global__ __launch_bounds__(256) void tok_kernel(
    const float* __restrict__ x, const float* __restrict__ l1w,
    const float* __restrict__ l1b, float* __restrict__ Q) {
    int idx = blockIdx.x * 256 + threadIdx.x;          // < B*T
    int b = idx >> 9, t = idx & 511;
    float x0 = x[2 * b], x1 = x[2 * b + 1];
    float v = fmaf(x0, l1w[2 * t], fmaf(x1, l1w[2 * t + 1], l1b[t]));
    Q[idx] = silu_f(v);
}

// ------- layernorm (fp32 in, f16 out, optional f16 lo residual), wave per row -------
template <bool LO>
__global__ __launch_bounds__(256) void ln_kernel(
    const float* __restrict__ X, const float* __restrict__ g,
    const float* __restrict__ bia, _Float16* __restrict__ Y,
    _Float16* __restrict__ Ylo) {
    int lane = threadIdx.x & 63;
    int row  = blockIdx.x * 4 + (threadIdx.x >> 6);
    const float* xr = X + (size_t)row * TT;
    float v[8];
    {
        float4 a = *(const float4*)(xr + lane * 8);
        float4 c = *(const float4*)(xr + lane * 8 + 4);
        v[0]=a.x; v[1]=a.y; v[2]=a.z; v[3]=a.w;
        v[4]=c.x; v[5]=c.y; v[6]=c.z; v[7]=c.w;
    }
    float s = 0.f;
    #pragma unroll
    for (int i = 0; i < 8; ++i) s += v[i];
    #pragma unroll
    for (int off = 32; off > 0; off >>= 1) s += __shfl_down(s, off);
    float mean = __shfl(s, 0) * (1.0f / TT);
    float ss = 0.f;
    #pragma unroll
    for (int i = 0; i < 8; ++i) { float d = v[i] - mean; ss = fmaf(d, d, ss); }
    #pragma unroll
    for (int off = 32; off > 0; off >>= 1) ss += __shfl_down(ss, off);
    float var  = __shfl(ss, 0) * (1.0f / TT);
    float rstd = rsqrtf(var + EPS_LN);
    half8 hv, lv;
    #pragma unroll
    for (int i = 0; i < 8; ++i) {
        int t = lane * 8 + i;
        float o = (v[i] - mean) * rstd * g[t] + bia[t];
        hv[i] = (_Float16)o;
        if (LO) lv[i] = (_Float16)(o - (float)hv[i]);
    }
    *(half8*)(Y + (size_t)row * TT + lane * 8) = hv;
    if (LO) *(half8*)(Ylo + (size_t)row * TT + lane * 8) = lv;
}

// --------------- 64x64-tile MFMA GEMM: C = act(A @ W^T + b) (+R) ---------------
// BM=BN=64, BK=32, 4 waves 2x2, wave tile 32x32, mfma 16x16x32 f16.
// Small footprint (16 KB LDS dbuf) -> many co-resident blocks per CU so
// barrier/vmcnt drains of one block overlap other blocks' compute.
// XOR chunk swizzle keeps fragment ds_read_b128 conflict-free (round-4 verified).
template <int ACT, bool RESID, typename OutT>
__global__ __launch_bounds__(256) void gemm64_kernel(
    const _Float16* __restrict__ A, const _Float16* __restrict__ W,
    const float* __restrict__ bias, const float* __restrict__ R,
    OutT* __restrict__ C, int N, int K) {
    __shared__ alignas(16) _Float16 As[2][64][32];
    __shared__ alignas(16) _Float16 Ws[2][64][32];

    const int tid = threadIdx.x;
    const int m0  = blockIdx.x * 64;
    const int n0  = blockIdx.y * 64;

    const int sr  = tid >> 2;                // staging row 0..63
    const int sc  = tid & 3;                 // 16B slot
    const int scs = sc ^ ((sr >> 1) & 3);    // swizzled source chunk

    const _Float16* Ag = A + (size_t)(m0 + sr) * K + scs * 8;
    const _Float16* Wg = W + (size_t)(n0 + sr) * K + scs * 8;

    const int wv   = tid >> 6;
    const int wm   = (wv >> 1) * 32;
    const int wn   = (wv & 1) * 32;
    const int lane = tid & 63;
    const int fr   = lane & 15;
    const int q    = lane >> 4;
    const int fk   = (q ^ ((fr >> 1) & 3)) * 8;

    f32x4 acc[2][2];
    #pragma unroll
    for (int mi = 0; mi < 2; ++mi)
        #pragma unroll
        for (int ni = 0; ni < 2; ++ni) acc[mi][ni] = {0.f, 0.f, 0.f, 0.f};

    auto stage = [&](int buf, int k0) {
        async16(&As[buf][sr][sc * 8], Ag + k0);
        async16(&Ws[buf][sr][sc * 8], Wg + k0);
    };

    stage(0, 0);
    const int NK = K / 32;
    for (int ki = 0; ki < NK; ++ki) {
        const int buf = ki & 1;
        __syncthreads();                        // drains prev stage
        if (ki + 1 < NK) stage(buf ^ 1, (ki + 1) * 32);
        half8 a[2], b[2];
        #pragma unroll
        for (int mi = 0; mi < 2; ++mi)
            a[mi] = *(const half8*)&As[buf][wm + mi * 16 + fr][fk];
        #pragma unroll
        for (int ni = 0; ni < 2; ++ni)
            b[ni] = *(const half8*)&Ws[buf][wn + ni * 16 + fr][fk];
        #pragma unroll
        for (int mi = 0; mi < 2; ++mi)
            #pragma unroll
            for (int ni = 0; ni < 2; ++ni)
                acc[mi][ni] = __builtin_amdgcn_mfma_f32_16x16x32_f16(
                    a[mi], b[ni], acc[mi][ni], 0, 0, 0);
    }

    const int r0 = q * 4;
    #pragma unroll
    for (int mi = 0; mi < 2; ++mi) {
        #pragma unroll
        for (int ni = 0; ni < 2; ++ni) {
            const int col = n0 + wn + ni * 16 + fr;
            const float bv = bias[col];
            #pragma unroll
            for (int r = 0; r < 4; ++r) {
                const int row = m0 + wm + mi * 16 + r0 + r;
                float v = acc[mi][ni][r] + bv;
                if (ACT == 1) v = silu_f(v);
                if (RESID) v += R[(size_t)row * N + col];
                C[(size_t)row * N + col] = (OutT)v;
            }
        }
    }
}

// --------- fused mu+sig dual-output SPLIT GEMM (near-fp32 from f16) ---------
// mu = tanh(A @ Wm^T + bm), sig = A @ Ws^T + bs, with A,W given as hi+lo f16
// pairs; acc = Ah@Wh + Al@Wh + Ah@Wl. Shares A staging across both outputs.
__global__ __launch_bounds__(256) void musig_kernel(
    const _Float16* __restrict__ Ah, const _Float16* __restrict__ Al,
    const _Float16* __restrict__ Wmh, const _Float16* __restrict__ Wml,
    const _Float16* __restrict__ Wsh, const _Float16* __restrict__ Wsl,
    const float* __restrict__ bm, const float* __restrict__ bs,
    float* __restrict__ Mu, float* __restrict__ Sg, int N, int K) {
    __shared__ alignas(16) _Float16 As[2][2][64][32];   // [buf][hi/lo]
    __shared__ alignas(16) _Float16 Ms[2][2][64][32];
    __shared__ alignas(16) _Float16 Ss[2][2][64][32];

    const int tid = threadIdx.x;
    const int m0  = blockIdx.x * 64;
    const int n0  = blockIdx.y * 64;

    const int sr  = tid >> 2;
    const int sc  = tid & 3;
    const int scs = sc ^ ((sr >> 1) & 3);

    const size_t aof = (size_t)(m0 + sr) * K + scs * 8;
    const size_t wof = (size_t)(n0 + sr) * K + scs * 8;

    const int wv   = tid >> 6;
    const int wm   = (wv >> 1) * 32;
    const int wn   = (wv & 1) * 32;
    const int lane = tid & 63;
    const int fr   = lane & 15;
    const int q    = lane >> 4;
    const int fk   = (q ^ ((fr >> 1) & 3)) * 8;

    f32x4 am[2][2], as_[2][2];
    #pragma unroll
    for (int mi = 0; mi < 2; ++mi)
        #pragma unroll
        for (int ni = 0; ni < 2; ++ni) {
            am[mi][ni]  = {0.f, 0.f, 0.f, 0.f};
            as_[mi][ni] = {0.f, 0.f, 0.f, 0.f};
        }

    auto stage = [&](int buf, int k0) {
        async16(&As[buf][0][sr][sc * 8], Ah  + aof + k0);
        async16(&As[buf][1][sr][sc * 8], Al  + aof + k0);
        async16(&Ms[buf][0][sr][sc * 8], Wmh + wof + k0);
        async16(&Ms[buf][1][sr][sc * 8], Wml + wof + k0);
        async16(&Ss[buf][0][sr][sc * 8], Wsh + wof + k0);
        async16(&Ss[buf][1][sr][sc * 8], Wsl + wof + k0);
    };

    stage(0, 0);
    const int NK = K / 32;
    for (int ki = 0; ki < NK; ++ki) {
        const int buf = ki & 1;
        __syncthreads();
        if (ki + 1 < NK) stage(buf ^ 1, (ki + 1) * 32);
        half8 ah[2], al[2], mh[2], ml[2], sh[2], sl[2];
        #pragma unroll
        for (int mi = 0; mi < 2; ++mi) {
            ah[mi] = *(const half8*)&As[buf][0][wm + mi * 16 + fr][fk];
            al[mi] = *(const half8*)&As[buf][1][wm + mi * 16 + fr][fk];
        }
        #pragma unroll
        for (int ni = 0; ni < 2; ++ni) {
            mh[ni] = *(const half8*)&Ms[buf][0][wn + ni * 16 + fr][fk];
            ml[ni] = *(const half8*)&Ms[buf][1][wn + ni * 16 + fr][fk];
            sh[ni] = *(const half8*)&Ss[buf][0][wn + ni * 16 + fr][fk];
            sl[ni] = *(const half8*)&Ss[buf][1][wn + ni * 16 + fr][fk];
        }
        #pragma unroll
        for (int mi = 0; mi < 2; ++mi)
            #pragma unroll
            for (int ni = 0; ni < 2; ++ni) {
                am[mi][ni] = __builtin_amdgcn_mfma_f32_16x16x32_f16(ah[mi], mh[ni], am[mi][ni], 0, 0, 0);
                am[mi][ni] = __builtin_amdgcn_mfma_f32_16x16x32_f16(al[mi], mh[ni], am[mi][ni], 0, 0, 0);
                am[mi][ni] = __builtin_amdgcn_mfma_f32_16x16x32_f16(ah[mi], ml[ni], am[mi][ni], 0, 0, 0);
                as_[mi][ni] = __builtin_amdgcn_mfma_f32_16x16x32_f16(ah[mi], sh[ni], as_[mi][ni], 0, 0, 0);
                as_[mi][ni] = __builtin_amdgcn_mfma_f32_16x16x32_f16(al[mi], sh[ni], as_[mi][ni], 0, 0, 0);
                as_[mi][ni] = __builtin_amdgcn_mfma_f32_16x16x32_f16(ah[mi], sl[ni], as_[mi][ni], 0, 0, 0);
            }
    }

    const int r0 = q * 4;
    #pragma unroll
    for (int mi = 0; mi < 2; ++mi) {
        #pragma unroll
        for (int ni = 0; ni < 2; ++ni) {
            const int col = n0 + wn + ni * 16 + fr;
            const float bmv = bm[col], bsv = bs[col];
            #pragma unroll
            for (int r = 0; r < 4; ++r) {
                const int row = m0 + wm + mi * 16 + r0 + r;
                Mu[(size_t)row * N + col] = tanhf(am[mi][ni][r] + bmv);
                Sg[(size_t)row * N + col] = as_[mi][ni][r] + bsv;
            }
        }
    }
}

// ------- Gaussian kernelized attention update: Q += sum_k S(G,mu,sig)*H -------
__global__ __launch_bounds__(256) void attn_kernel(
    float* __restrict__ Q, const float* __restrict__ mu_,
    const float* __restrict__ sig_, const float* __restrict__ x,
    const float* __restrict__ omega, const float* __restrict__ G,
    const float* __restrict__ phase) {
    __shared__ float cs[8][260];
    __shared__ float gs[8][260];
    const int tid = threadIdx.x;
    const int b   = blockIdx.x >> 1;
    const int t0  = (blockIdx.x & 1) * 256;
    const float x0 = x[2 * b], x1 = x[2 * b + 1];
    #pragma unroll
    for (int it = 0; it < 8; ++it) {
        int j = it * 256 + tid;            // 0..2047
        int e = t0 * 8 + j;                // flat (t,k) index
        float2 om = *(const float2*)(omega + 2 * e);
        float arg = fmaf(om.x, x0, fmaf(om.y, x1, phase[e]));
        cs[j & 7][j >> 3] = __cosf(arg);
        gs[j & 7][j >> 3] = G[e];
    }
    __syncthreads();
    const int idx = blockIdx.x * 256 + tid;   // = b*512 + t0 + tid
    float mu  = mu_[idx];
    float sig = sig_[idx];
    float inv = -0.5f * __builtin_amdgcn_rcpf(fmaf(sig, sig, EPS_SIG));
    float acc = 0.f;
    #pragma unroll
    for (int k = 0; k < 8; ++k) {
        float d = gs[k][tid] - mu;
        acc = fmaf(__expf(d * d * inv), cs[k][tid], acc);
    }
    Q[idx] += acc;
}

// ---------------- readout: out[b] = silu(Q[b,:]) . ro_w + ro_b ----------------
__global__ __launch_bounds__(256) void readout_kernel(
    const float* __restrict__ Q, const float* __restrict__ row_,
    const float* __restrict__ rob, float* __restrict__ out) {
    int lane = threadIdx.x & 63;
    int row  = blockIdx.x * 4 + (threadIdx.x >> 6);
    const float* qr = Q + (size_t)row * TT;
    float acc = 0.f;
    #pragma unroll
    for (int i = 0; i < 8; ++i) {
        int t = lane * 8 + i;
        acc = fmaf(silu_f(qr[t]), row_[t], acc);
    }
    #pragma unroll
    for (int off = 32; off > 0; off >>= 1) acc += __shfl_down(acc, off);
    if (lane == 0) out[row] = acc + rob[0];
}

} // namespace

extern "C" void kernel_launch(void* const* d_in, const int* in_sizes, int n_in,
                              void* d_out, int out_size, void* d_ws, size_t ws_size,
                              hipStream_t stream) {
    const float* x     = (const float*)d_in[0];
    const float* omega = (const float*)d_in[1];
    const float* G     = (const float*)d_in[2];
    const float* phase = (const float*)d_in[3];
    const float* l1_w  = (const float*)d_in[4];
    const float* l1_b  = (const float*)d_in[5];
    const float* mu_w  = (const float*)d_in[6];
    const float* mu_b  = (const float*)d_in[7];
    const float* sg_w  = (const float*)d_in[8];
    const float* sg_b  = (const float*)d_in[9];
    const float* alqg  = (const float*)d_in[10];
    const float* alqb  = (const float*)d_in[11];
    const float* alfg  = (const float*)d_in[12];
    const float* alfb  = (const float*)d_in[13];
    const float* a_w1  = (const float*)d_in[14];
    const float* a_b1  = (const float*)d_in[15];
    const float* a_w2  = (const float*)d_in[16];
    const float* a_b2  = (const float*)d_in[17];
    const float* mln_g = (const float*)d_in[18];
    const float* mln_b = (const float*)d_in[19];
    const float* m_w1  = (const float*)d_in[20];
    const float* m_b1  = (const float*)d_in[21];
    const float* m_w2  = (const float*)d_in[22];
    const float* m_b2  = (const float*)d_in[23];
    const float* ro_w  = (const float*)d_in[24];
    const float* ro_b  = (const float*)d_in[25];

    // ---- workspace layout (total 100,663,296 B == round-1 proven footprint) ----
    char* ws = (char*)d_ws;
    float*     Q    = (float*)ws;                          // 16 MB  [B,T] fp32
    _Float16*  h_hi = (_Float16*)(ws + 16777216);          //  8 MB  [B,T] f16
    _Float16*  h_lo = (_Float16*)(ws + 25165824);          //  8 MB  [B,T] f16
    _Float16*  mid  = (_Float16*)(ws + 33554432);          // 32 MB  [B,F] f16
    float*     mu   = (float*)(ws + 33554432);             // alias on mid
    float*     sig  = (float*)(ws + 50331648);             // alias on mid
    _Float16*  wbuf = (_Float16*)(ws + 67108864);          // 32 MB  f16 weights

    _Float16* muw_hi = wbuf;                     // 4*512*512
    _Float16* muw_lo = muw_hi + 1048576;
    _Float16* sgw_hi = muw_lo + 1048576;
    _Float16* sgw_lo = sgw_hi + 1048576;
    _Float16* aw1    = sgw_lo + 1048576;         // 4*2048*512
    _Float16* aw2    = aw1 + 4194304;
    _Float16* mw1    = aw2 + 4194304;            // 2*2048*512
    _Float16* mw2    = mw1 + 2097152;

    dim3 blk(256);

    // weight conversion (re-done every call; inputs are re-poisoned by harness)
    cvt_kernel<true ><<<1024, blk, 0, stream>>>(mu_w, muw_hi, muw_lo, 1048576);
    cvt_kernel<true ><<<1024, blk, 0, stream>>>(sg_w, sgw_hi, sgw_lo, 1048576);
    cvt_kernel<false><<<4096, blk, 0, stream>>>(a_w1, aw1, nullptr, 4194304);
    cvt_kernel<false><<<4096, blk, 0, stream>>>(a_w2, aw2, nullptr, 4194304);
    cvt_kernel<false><<<2048, blk, 0, stream>>>(m_w1, mw1, nullptr, 2097152);
    cvt_kernel<false><<<2048, blk, 0, stream>>>(m_w2, mw2, nullptr, 2097152);

    tok_kernel<<<BB * TT / 256, blk, 0, stream>>>(x, l1_w, l1_b, Q);

    for (int i = 0; i < 4; ++i) {
        ln_kernel<true><<<BB / 4, blk, 0, stream>>>(
            Q, alqg + i * TT, alqb + i * TT, h_hi, h_lo);
        musig_kernel<<<dim3(BB / 64, TT / 64), blk, 0, stream>>>(
            h_hi, h_lo,
            muw_hi + (size_t)i * 262144, muw_lo + (size_t)i * 262144,
            sgw_hi + (size_t)i * 262144, sgw_lo + (size_t)i * 262144,
            mu_b + i * TT, sg_b + i * TT, mu, sig, TT, TT);
        attn_kernel<<<BB * TT / 256, blk, 0, stream>>>(Q, mu, sig, x, omega, G, phase);
        ln_kernel<false><<<BB / 4, blk, 0, stream>>>(
            Q, alfg + i * TT, alfb + i * TT, h_hi, nullptr);
        gemm64_kernel<1, false, _Float16><<<dim3(BB / 64, FF / 64), blk, 0, stream>>>(
            h_hi, aw1 + (size_t)i * 1048576, a_b1 + i * FF, nullptr, mid, FF, TT);
        gemm64_kernel<0, true, float><<<dim3(BB / 64, TT / 64), blk, 0, stream>>>(
            mid, aw2 + (size_t)i * 1048576, a_b2 + i * TT, Q, Q, TT, FF);
    }
    for (int i = 0; i < 2; ++i) {
        ln_kernel<false><<<BB / 4, blk, 0, stream>>>(
            Q, mln_g + i * TT, mln_b + i * TT, h_hi, nullptr);
        gemm64_kernel<1, false, _Float16><<<dim3(BB / 64, FF / 64), blk, 0, stream>>>(
            h_hi, mw1 + (size_t)i * 1048576, m_b1 + i * FF, nullptr, mid, FF, TT);
        gemm64_kernel<0, true, float><<<dim3(BB / 64, TT / 64), blk, 0, stream>>>(
            mid, mw2 + (size_t)i * 1048576, m_b2 + i * TT, Q, Q, TT, FF);
    }

    readout_kernel<<<BB / 4, blk, 0, stream>>>(Q, ro_w, ro_b, (float*)d_out);
}